// Round 1
// baseline (64.981 us; speedup 1.0000x reference)
//
#include <hip/hip_runtime.h>
#include <math.h>

namespace {

constexpr int C = 25;

struct Ws {
  int    last_neg;   // offset 0
  int    pad0;
  double ce_sum;     // offset 8
  double tail_sum;   // offset 16
  float  norm_last;  // offset 24
};

__global__ void k_init(Ws* ws) {
  ws->last_neg  = -1;
  ws->ce_sum    = 0.0;
  ws->tail_sum  = 0.0;
  ws->norm_last = 0.0f;
}

// Find max pair index with labels[2p] != labels[2p+1].
__global__ __launch_bounds__(256)
void k_lastneg(const int* __restrict__ labels, int P, Ws* __restrict__ ws) {
  int best = -1;
  for (int p = blockIdx.x * blockDim.x + threadIdx.x; p < P;
       p += gridDim.x * blockDim.x) {
    int2 l = reinterpret_cast<const int2*>(labels)[p];
    if (l.x != l.y) best = p;  // p increases monotonically per thread
  }
#pragma unroll
  for (int off = 32; off; off >>= 1)
    best = max(best, __shfl_down(best, off, 64));
  __shared__ int smax[4];
  const int lane = threadIdx.x & 63, wid = threadIdx.x >> 6;
  if (lane == 0) smax[wid] = best;
  __syncthreads();
  if (threadIdx.x == 0) {
    int b = max(max(smax[0], smax[1]), max(smax[2], smax[3]));
    atomicMax(&ws->last_neg, b);
  }
}

// Main fused pass: one thread per pair (rows 2p, 2p+1).
__global__ __launch_bounds__(256)
void k_main(const float* __restrict__ x, const int* __restrict__ labels,
            const float* __restrict__ M, int P, Ws* __restrict__ ws) {
  __shared__ float colsq[C];
  if (threadIdx.x < C) {
    float s = 0.f;
    for (int r = 0; r < C; ++r) {
      float m = M[r * C + threadIdx.x];
      s += m * m;
    }
    colsq[threadIdx.x] = s;
  }
  __syncthreads();

  const int last_neg = ws->last_neg;

  float  ce_local   = 0.f;
  double tail_local = 0.0;

  for (int p = blockIdx.x * blockDim.x + threadIdx.x; p < P;
       p += gridDim.x * blockDim.x) {
    const size_t base = (size_t)p * (2 * C);
    const int2 l = reinterpret_cast<const int2*>(labels)[p];

    // Load both rows (50 consecutive floats) as 25 x float2 (8B/lane).
    float e[2 * C];
    const float2* src = reinterpret_cast<const float2*>(x + base);
#pragma unroll
    for (int j = 0; j < C; ++j) {
      float2 v  = src[j];
      e[2 * j]     = v.x;
      e[2 * j + 1] = v.y;
    }

    // log-softmax label terms for both rows
    float ma = -INFINITY, mb = -INFINITY;
#pragma unroll
    for (int c = 0; c < C; ++c) {
      ma = fmaxf(ma, e[c]);
      mb = fmaxf(mb, e[C + c]);
    }
    float sa = 0.f, sb = 0.f;
#pragma unroll
    for (int c = 0; c < C; ++c) {
      sa += __expf(e[c] - ma);
      sb += __expf(e[C + c] - mb);
    }
    const float lse_a = ma + __logf(sa);
    const float lse_b = mb + __logf(sb);
    // label logits: re-load from global (L1-hot) to avoid dynamic reg indexing
    const float xa = x[base + (size_t)l.x];
    const float xb = x[base + C + (size_t)l.y];
    ce_local += (lse_a - xa) + (lse_b - xb);

    // Pair (Mahalanobis-ish) distance — only where it matters:
    if (l.x == l.y) {
      if (p > last_neg) {
        float s = 0.f;
#pragma unroll
        for (int c = 0; c < C; ++c) {
          float d = e[c] - e[C + c];
          s = fmaf(d * d, colsq[c], s);
        }
        tail_local += (double)sqrtf(s);
      }
    } else if (p == last_neg) {
      float s = 0.f;
#pragma unroll
      for (int c = 0; c < C; ++c) {
        float d = e[c] - e[C + c];
        s = fmaf(d * d, colsq[c], s);
      }
      ws->norm_last = sqrtf(s);
    }
  }

  // block-reduce ce (float within block, double atomic across blocks)
#pragma unroll
  for (int off = 32; off; off >>= 1)
    ce_local += __shfl_down(ce_local, off, 64);
  __shared__ float wce[4];
  const int lane = threadIdx.x & 63, wid = threadIdx.x >> 6;
  if (lane == 0) wce[wid] = ce_local;
  __syncthreads();
  if (threadIdx.x == 0) {
    float bs = (wce[0] + wce[1]) + (wce[2] + wce[3]);
    atomicAdd(&ws->ce_sum, (double)bs);
  }
  if (tail_local != 0.0) atomicAdd(&ws->tail_sum, tail_local);
}

__global__ void k_fin(const Ws* __restrict__ ws, float* __restrict__ out,
                      float invB) {
  double ce = ws->ce_sum * (double)invB;
  float ml = 1.0f + (float)ws->tail_sum - ws->norm_last;
  ml = fmaxf(ml, 0.0f);
  out[0] = (float)(ce + 0.005 * (double)ml);
}

}  // namespace

extern "C" void kernel_launch(void* const* d_in, const int* in_sizes, int n_in,
                              void* d_out, int out_size, void* d_ws,
                              size_t ws_size, hipStream_t stream) {
  const float* x      = (const float*)d_in[0];
  const int*   labels = (const int*)d_in[1];
  const float* M      = (const float*)d_in[2];
  float*       out    = (float*)d_out;
  Ws*          ws     = (Ws*)d_ws;

  const int B = in_sizes[1];
  const int P = B / 2;

  k_init<<<1, 1, 0, stream>>>(ws);
  k_lastneg<<<1024, 256, 0, stream>>>(labels, P, ws);
  const int blocks = 2048;  // grid-stride, ~8 blocks/CU worth of waves
  k_main<<<blocks, 256, 0, stream>>>(x, labels, M, P, ws);
  k_fin<<<1, 1, 0, stream>>>(ws, out, 1.0f / (float)B);
}